// Round 18
// baseline (58172.620 us; speedup 1.0000x reference)
//
#include <hip/hip_runtime.h>
#include <math.h>

#define T_STEPS 16384
#define IN 512
#define HID 1024
#define NC 512
#define NWG 256
#define TPB 256
typedef unsigned long long ull;

// Fast activations: v_exp_f32 + v_rcp_f32 (verified r15: absmax unchanged).
__device__ __forceinline__ float sigmoid_f(float x) {
    return __builtin_amdgcn_rcpf(1.f + __expf(-x));
}
__device__ __forceinline__ float tanh_f(float x) {
    return 1.f - 2.f * __builtin_amdgcn_rcpf(1.f + __expf(2.f * x));
}

// DPP wave reduce: 6 VALU-speed steps, total lands in lane 63 (verified r15).
template <int CTRL>
__device__ __forceinline__ float dpp_add_(float x) {
    int y = __builtin_amdgcn_update_dpp(0, __float_as_int(x), CTRL, 0xf, 0xf, true);
    return x + __int_as_float(y);
}
__device__ __forceinline__ float wave_sum_l63(float x) {
    x = dpp_add_<0x111>(x);  // row_shr:1
    x = dpp_add_<0x112>(x);  // row_shr:2
    x = dpp_add_<0x114>(x);  // row_shr:4
    x = dpp_add_<0x118>(x);  // row_shr:8
    x = dpp_add_<0x142>(x);  // row_bcast15
    x = dpp_add_<0x143>(x);  // row_bcast31 -> lane63 = total
    return x;
}

// ---------------- Kernel 0: seed epoch-tagged h buffer ----------------
// bufp[p][j] = {epoch:u32 | h:f32}. Step t polls parity t&1 for epoch>=t+1;
// publishes epoch t+2 at parity (t+1)&1. h0 -> epoch 1, parity 0.
// ws is NOT re-poisoned between replays -> reset both parities every launch.
__global__ void init_k(const float* __restrict__ h0, ull* __restrict__ bufp)
{
    const int j = threadIdx.x;  // 1024 threads, 1 block
    bufp[j]       = (1ull << 32) | (ull)__float_as_uint(h0[j]);
    bufp[HID + j] = 0ull;
}

// ---------------- Kernel 1: persistent LSTM recurrence + fused dense ----------------
// r18 = r15 (best, 30.9k) + software-pipelined poll seed: the next step's
// first 4 sample loads are ISSUED right after the publish (before dense +
// heater), carried in pre[4] into the next spin as its seed. Detection's
// first MALL round trip overlaps dense+heater instead of following them.
// Spin logic itself is byte-identical to r15 (r16/r17's restructured spins
// both regressed). Keeps: LDS stage + 1 barrier, DPP lane-63 reduce, fast
// activations, RMW publish, DVFS heaters (r13: heater = 70.5k -> 42.0k).
__global__ __launch_bounds__(TPB, 1) void lstm_rec(
    const float* __restrict__ X,     // [T, IN]
    const float* __restrict__ c0,    // [HID]
    const float* __restrict__ W_ih,  // [4H, IN]
    const float* __restrict__ W_hh,  // [4H, HID]
    const float* __restrict__ b_ih,  // [4H]
    const float* __restrict__ b_hh,  // [4H]
    const float* __restrict__ Wd,    // [NC, HID]
    const float* __restrict__ bd,    // [NC]
    float* __restrict__ logits,      // ws [T, NC]
    ull* __restrict__ bufp)          // ws [2][HID] epoch|h
{
    __shared__ float svh[2][HID];    // double-buffered staged h

    const int tid  = threadIdx.x;
    const int wg   = blockIdx.x;
    const int lane = tid & 63;
    const int wv   = tid >> 6;
    const int j    = wg * 4 + wv;    // owned h element
    const int kb   = lane * 4;

    // --- gate weights for the 4 rows of elem j: lane covers k=kb+c*256 ---
    float4 w[4][6];
    float bias[4];
    #pragma unroll
    for (int q = 0; q < 4; ++q) {
        const int row = q * HID + j;
        #pragma unroll
        for (int c = 0; c < 6; ++c) {
            const int k = kb + c * 256;
            w[q][c] = (k < IN)
                ? *(const float4*)&W_ih[(size_t)row * IN + k]
                : *(const float4*)&W_hh[(size_t)row * HID + (k - IN)];
        }
        bias[q] = b_ih[row] + b_hh[row];
    }

    // --- dense weights: wave wv<2 owns C-row wg*2+wv (16 floats/lane) ---
    const int drow = wg * 2 + wv;
    float4 wd[4];
    float dbias = 0.f;
    if (wv < 2) {
        #pragma unroll
        for (int c = 0; c < 4; ++c)
            wd[c] = *(const float4*)&Wd[(size_t)drow * HID + kb + c * 256];
        dbias = bd[drow];
    }

    float c_state = c0[j];   // lane 63's evolution is the live one
    bool dead = false;
    // heater state (kept alive by asm; never affects results)
    float hx0 = 1.0f + (float)tid * 1e-8f;
    float hx1 = 1.1f, hx2 = 1.2f, hx3 = 1.3f;

    // seed sample for step 0 (parity 0; init_k already wrote epoch 1 there)
    ull pre[4];
    #pragma unroll
    for (int c = 0; c < 4; ++c)
        pre[c] = __hip_atomic_load(&bufp[tid + 256 * c],
                                   __ATOMIC_RELAXED, __HIP_MEMORY_SCOPE_AGENT);

    // one extra pseudo-step (t == T_STEPS) computes logits[T-1] only
    for (int t = 0; t <= T_STEPS; ++t) {
        const int p = t & 1;
        const unsigned want = (unsigned)(t + 1);
        const bool live = (t < T_STEPS);

        float4 x0, x1;
        if (live) {   // x prefetch (overlaps the spin)
            const float* xr = X + (size_t)t * IN;
            x0 = *(const float4*)&xr[kb];
            x1 = *(const float4*)&xr[kb + 256];
        }

        // ---- thread-local spin, seeded by the prefetched sample (r15 logic) ----
        ull* src = bufp + (size_t)p * HID;
        ull v[4];
        #pragma unroll
        for (int c = 0; c < 4; ++c) v[c] = pre[c];
        unsigned spn = 0;
        for (;;) {
            bool all = true;
            #pragma unroll
            for (int c = 0; c < 4; ++c) {
                if ((unsigned)(v[c] >> 32) < want) {
                    all = false;
                    v[c] = __hip_atomic_load(&src[tid + 256 * c],
                                             __ATOMIC_RELAXED, __HIP_MEMORY_SCOPE_AGENT);
                }
            }
            if (all || dead) break;
            // heater: 32 dependent FMAs while the reloads are in flight (r13)
            #pragma unroll
            for (int u = 0; u < 32; ++u) hx0 = __builtin_fmaf(hx0, 1.0000001f, 1.0e-9f);
            asm volatile("" : "+v"(hx0));
            if (++spn > 500000u) dead = true;   // fail, don't hang
        }
        // one LDS write + ONE barrier per step (r15 rendezvous)
        #pragma unroll
        for (int c = 0; c < 4; ++c)
            svh[p][tid + 256 * c] = __uint_as_float((unsigned)v[c]);
        __syncthreads();

        const float4 s2 = *(const float4*)&svh[p][kb];
        const float4 s3 = *(const float4*)&svh[p][kb + 256];
        const float4 s4 = *(const float4*)&svh[p][kb + 512];
        const float4 s5 = *(const float4*)&svh[p][kb + 768];

        if (live) {
            // ---- gates GEMV: 4 rows, weights + h in regs ----
            float acc[4];
            #pragma unroll
            for (int q = 0; q < 4; ++q) {
                acc[q] = w[q][0].x*x0.x + w[q][0].y*x0.y + w[q][0].z*x0.z + w[q][0].w*x0.w
                       + w[q][1].x*x1.x + w[q][1].y*x1.y + w[q][1].z*x1.z + w[q][1].w*x1.w
                       + w[q][2].x*s2.x + w[q][2].y*s2.y + w[q][2].z*s2.z + w[q][2].w*s2.w
                       + w[q][3].x*s3.x + w[q][3].y*s3.y + w[q][3].z*s3.z + w[q][3].w*s3.w
                       + w[q][4].x*s4.x + w[q][4].y*s4.y + w[q][4].z*s4.z + w[q][4].w*s4.w
                       + w[q][5].x*s5.x + w[q][5].y*s5.y + w[q][5].z*s5.z + w[q][5].w*s5.w;
            }
            // DPP reduce: totals land in lane 63
            acc[0] = wave_sum_l63(acc[0]);
            acc[1] = wave_sum_l63(acc[1]);
            acc[2] = wave_sum_l63(acc[2]);
            acc[3] = wave_sum_l63(acc[3]);
            const float iv = sigmoid_f(acc[0] + bias[0]);
            const float fv = sigmoid_f(acc[1] + bias[1]);
            const float gv = tanh_f   (acc[2] + bias[2]);
            const float ov = sigmoid_f(acc[3] + bias[3]);
            c_state = fv * c_state + iv * gv;
            const float h = ov * tanh_f(c_state);
            if (lane == 63) {  // publish FIRST: RMW executes at the MALL
                (void)__hip_atomic_exchange(&bufp[(size_t)(p ^ 1) * HID + j],
                    ((ull)(unsigned)(t + 2) << 32) | (ull)__float_as_uint(h),
                    __ATOMIC_RELAXED, __HIP_MEMORY_SCOPE_AGENT);
            }
        }

        // ---- software-pipelined poll seed for step t+1 (parity p^1):
        // issued NOW so the first detection round trip overlaps dense+heater.
        {
            ull* src2 = bufp + (size_t)(p ^ 1) * HID;
            #pragma unroll
            for (int c = 0; c < 4; ++c)
                pre[c] = __hip_atomic_load(&src2[tid + 256 * c],
                                           __ATOMIC_RELAXED, __HIP_MEMORY_SCOPE_AGENT);
        }

        // ---- fused dense: logits[t-1] rows {wg*2, wg*2+1} (wait window) ----
        if (t > 0 && wv < 2) {
            float d = wd[0].x*s2.x + wd[0].y*s2.y + wd[0].z*s2.z + wd[0].w*s2.w
                    + wd[1].x*s3.x + wd[1].y*s3.y + wd[1].z*s3.z + wd[1].w*s3.w
                    + wd[2].x*s4.x + wd[2].y*s4.y + wd[2].z*s4.z + wd[2].w*s4.w
                    + wd[3].x*s5.x + wd[3].y*s5.y + wd[3].z*s5.z + wd[3].w*s5.w;
            d = wave_sum_l63(d);
            if (lane == 63)
                logits[(size_t)(t - 1) * NC + drow] = d + dbias;
        }

        // ---- post-publish heater: 4 parallel chains x 128 FMAs (r13) ----
        if (live) {
            #pragma unroll
            for (int u = 0; u < 128; ++u) {
                hx0 = __builtin_fmaf(hx0, 1.0000001f, 1.0e-9f);
                hx1 = __builtin_fmaf(hx1, 1.0000001f, 1.0e-9f);
                hx2 = __builtin_fmaf(hx2, 1.0000001f, 1.0e-9f);
                hx3 = __builtin_fmaf(hx3, 1.0000001f, 1.0e-9f);
            }
            asm volatile("" : "+v"(hx0), "+v"(hx1), "+v"(hx2), "+v"(hx3));
        }
    }
}

// ---------------- Kernel 2: P[t] = softmax_C(logits[t]) ----------------
__global__ __launch_bounds__(256) void softmaxC_k(
    const float* __restrict__ logits, float* __restrict__ P)
{
    const int tid = threadIdx.x;
    const int lane = tid & 63, wvv = tid >> 6;
    #pragma unroll
    for (int rr = 0; rr < 2; ++rr) {
        const int row = blockIdx.x * 8 + wvv * 2 + rr;
        const float4 a = *(const float4*)&logits[(size_t)row * NC + lane * 8];
        const float4 b = *(const float4*)&logits[(size_t)row * NC + lane * 8 + 4];
        float m = fmaxf(fmaxf(fmaxf(a.x, a.y), fmaxf(a.z, a.w)),
                        fmaxf(fmaxf(b.x, b.y), fmaxf(b.z, b.w)));
        #pragma unroll
        for (int off = 32; off; off >>= 1) m = fmaxf(m, __shfl_xor(m, off));
        float4 ea, eb;
        ea.x = expf(a.x - m); ea.y = expf(a.y - m); ea.z = expf(a.z - m); ea.w = expf(a.w - m);
        eb.x = expf(b.x - m); eb.y = expf(b.y - m); eb.z = expf(b.z - m); eb.w = expf(b.w - m);
        float s = ea.x + ea.y + ea.z + ea.w + eb.x + eb.y + eb.z + eb.w;
        #pragma unroll
        for (int off = 32; off; off >>= 1) s += __shfl_xor(s, off);
        const float inv = 1.f / s;
        ea.x *= inv; ea.y *= inv; ea.z *= inv; ea.w *= inv;
        eb.x *= inv; eb.y *= inv; eb.z *= inv; eb.w *= inv;
        *(float4*)&P[(size_t)row * NC + lane * 8]     = ea;
        *(float4*)&P[(size_t)row * NC + lane * 8 + 4] = eb;
    }
}

// ---------------- Kernel 3a: colsum[c] = sum_t exp(P[t][c]) ----------------
__global__ __launch_bounds__(256) void colsum_k(const float* __restrict__ P, float* __restrict__ cs)
{
    const int tid = threadIdx.x;
    const int c  = blockIdx.x * 16 + (tid & 15);
    const int tr = tid >> 4;
    float s = 0.f;
    #pragma unroll 8
    for (int t = tr; t < T_STEPS; t += 16) s += expf(P[(size_t)t * NC + c]);
    __shared__ float red[256];
    red[tid] = s; __syncthreads();
    for (int off = 128; off >= 16; off >>= 1) {
        if (tid < off) red[tid] += red[tid + off];
        __syncthreads();
    }
    if (tid < 16) cs[blockIdx.x * 16 + tid] = red[tid];
}

// ---------------- Kernel 3b: out = exp(P) / colsum ----------------
__global__ __launch_bounds__(256) void norm_k(float* P, const float* __restrict__ cs)
{
    size_t i = (size_t)blockIdx.x * 256 + threadIdx.x;
    const size_t n = (size_t)T_STEPS * NC;
    const size_t stride = (size_t)gridDim.x * 256;
    for (; i < n; i += stride) P[i] = expf(P[i]) / cs[i & (NC - 1)];
}

extern "C" void kernel_launch(void* const* d_in, const int* in_sizes, int n_in,
                              void* d_out, int out_size, void* d_ws, size_t ws_size,
                              hipStream_t stream) {
    const float* X    = (const float*)d_in[0];
    const float* h0   = (const float*)d_in[1];
    const float* c0   = (const float*)d_in[2];
    const float* W_ih = (const float*)d_in[3];
    const float* W_hh = (const float*)d_in[4];
    const float* b_ih = (const float*)d_in[5];
    const float* b_hh = (const float*)d_in[6];
    const float* Wd   = (const float*)d_in[7];
    const float* bd   = (const float*)d_in[8];
    float* out = (float*)d_out;

    char* ws = (char*)d_ws;
    ull*   bufp   = (ull*)ws;                    // [2][HID] epoch|h (16 KB)
    float* cs     = (float*)(ws + 16384);        // [NC]
    float* logits = (float*)(ws + 32768);        // [T, NC] (33.5 MB)

    init_k<<<1, HID, 0, stream>>>(h0, bufp);
    lstm_rec<<<NWG, TPB, 0, stream>>>(X, c0, W_ih, W_hh, b_ih, b_hh, Wd, bd, logits, bufp);
    softmaxC_k<<<T_STEPS / 8, 256, 0, stream>>>(logits, out);
    colsum_k<<<NC / 16, 256, 0, stream>>>(out, cs);
    norm_k<<<2048, 256, 0, stream>>>(out, cs);
}

// Round 19
// 30708.292 us; speedup vs baseline: 1.8944x; 1.8944x over previous
//
#include <hip/hip_runtime.h>
#include <math.h>

#define T_STEPS 16384
#define IN 512
#define HID 1024
#define NC 512
#define NWG 256
#define TPB 256
typedef unsigned long long ull;

// Fast activations: v_exp_f32 + v_rcp_f32 (~1ulp each). Double-softmax output
// contraction makes gate-level ~1e-6 rel error invisible at output (verified
// r15: absmax unchanged at 4.77e-7).
__device__ __forceinline__ float sigmoid_f(float x) {
    return __builtin_amdgcn_rcpf(1.f + __expf(-x));
}
__device__ __forceinline__ float tanh_f(float x) {
    return 1.f - 2.f * __builtin_amdgcn_rcpf(1.f + __expf(2.f * x));
}

// DPP wave reduce: 6 VALU-speed steps, total lands in lane 63 (verified r15).
template <int CTRL>
__device__ __forceinline__ float dpp_add_(float x) {
    int y = __builtin_amdgcn_update_dpp(0, __float_as_int(x), CTRL, 0xf, 0xf, true);
    return x + __int_as_float(y);
}
__device__ __forceinline__ float wave_sum_l63(float x) {
    x = dpp_add_<0x111>(x);  // row_shr:1
    x = dpp_add_<0x112>(x);  // row_shr:2
    x = dpp_add_<0x114>(x);  // row_shr:4
    x = dpp_add_<0x118>(x);  // row_shr:8  -> lane15 of each row = row sum
    x = dpp_add_<0x142>(x);  // row_bcast15
    x = dpp_add_<0x143>(x);  // row_bcast31 -> lane63 = total
    return x;
}

// ---------------- Kernel 0: seed epoch-tagged h buffer ----------------
// bufp[p][j] = {epoch:u32 | h:f32}. Step t publishes epoch t+2 at parity
// (t+1)&1; step t polls epoch t+1 at parity t&1. h0 -> epoch 1, parity 0.
// ws is NOT re-poisoned between replays -> reset both parities every launch.
__global__ void init_k(const float* __restrict__ h0, ull* __restrict__ bufp)
{
    const int j = threadIdx.x;  // 1024 threads, 1 block
    bufp[j]       = (1ull << 32) | (ull)__float_as_uint(h0[j]);
    bufp[HID + j] = 0ull;
}

// ---------------- Kernel 1: persistent LSTM recurrence + fused dense ----------------
// r19 = r15 verbatim (the 30.9k champion). Ledger: r16 (lane-local poll,
// 43.8k), r17 (dual-stream, 37.7k), r18 (pre-seeded poll, 58.2k) all lost to
// this structure — any added in-flight load pressure or restructured spin
// lengthens the sweep. Champion structure: thread-local 4-word selective
// reload spin + 32-FMA heater, one LDS stage + one barrier, DPP lane-63
// reduce, fast activations, RMW publish, post-publish DVFS heater.
__global__ __launch_bounds__(TPB, 1) void lstm_rec(
    const float* __restrict__ X,     // [T, IN]
    const float* __restrict__ c0,    // [HID]
    const float* __restrict__ W_ih,  // [4H, IN]
    const float* __restrict__ W_hh,  // [4H, HID]
    const float* __restrict__ b_ih,  // [4H]
    const float* __restrict__ b_hh,  // [4H]
    const float* __restrict__ Wd,    // [NC, HID]
    const float* __restrict__ bd,    // [NC]
    float* __restrict__ logits,      // ws [T, NC]
    ull* __restrict__ bufp)          // ws [2][HID] epoch|h
{
    __shared__ float svh[2][HID];    // double-buffered staged h

    const int tid  = threadIdx.x;
    const int wg   = blockIdx.x;
    const int lane = tid & 63;
    const int wv   = tid >> 6;
    const int j    = wg * 4 + wv;    // owned h element
    const int kb   = lane * 4;

    // --- gate weights for the 4 rows of elem j: lane covers k=kb+c*256 ---
    float4 w[4][6];
    float bias[4];
    #pragma unroll
    for (int q = 0; q < 4; ++q) {
        const int row = q * HID + j;
        #pragma unroll
        for (int c = 0; c < 6; ++c) {
            const int k = kb + c * 256;
            w[q][c] = (k < IN)
                ? *(const float4*)&W_ih[(size_t)row * IN + k]
                : *(const float4*)&W_hh[(size_t)row * HID + (k - IN)];
        }
        bias[q] = b_ih[row] + b_hh[row];
    }

    // --- dense weights: wave wv<2 owns C-row wg*2+wv (16 floats/lane) ---
    const int drow = wg * 2 + wv;
    float4 wd[4];
    float dbias = 0.f;
    if (wv < 2) {
        #pragma unroll
        for (int c = 0; c < 4; ++c)
            wd[c] = *(const float4*)&Wd[(size_t)drow * HID + kb + c * 256];
        dbias = bd[drow];
    }

    float c_state = c0[j];   // lane 63's evolution is the live one
    bool dead = false;
    // heater state (kept alive by asm; never affects results)
    float hx0 = 1.0f + (float)tid * 1e-8f;
    float hx1 = 1.1f, hx2 = 1.2f, hx3 = 1.3f;

    // one extra pseudo-step (t == T_STEPS) computes logits[T-1] only
    for (int t = 0; t <= T_STEPS; ++t) {
        const int p = t & 1;
        const unsigned want = (unsigned)(t + 1);
        const bool live = (t < T_STEPS);

        float4 x0, x1;
        if (live) {   // x prefetch (overlaps the spin)
            const float* xr = X + (size_t)t * IN;
            x0 = *(const float4*)&xr[kb];
            x1 = *(const float4*)&xr[kb + 256];
        }

        // ---- thread-local spin on this thread's 4 fused words + heater ----
        ull* src = bufp + (size_t)p * HID;
        ull v[4];
        #pragma unroll
        for (int c = 0; c < 4; ++c)
            v[c] = __hip_atomic_load(&src[tid + 256 * c],
                                     __ATOMIC_RELAXED, __HIP_MEMORY_SCOPE_AGENT);
        unsigned spn = 0;
        for (;;) {
            bool all = true;
            #pragma unroll
            for (int c = 0; c < 4; ++c) {
                if ((unsigned)(v[c] >> 32) < want) {
                    all = false;
                    v[c] = __hip_atomic_load(&src[tid + 256 * c],
                                             __ATOMIC_RELAXED, __HIP_MEMORY_SCOPE_AGENT);
                }
            }
            if (all || dead) break;
            // heater: 32 dependent FMAs while the reloads are in flight (r13)
            #pragma unroll
            for (int u = 0; u < 32; ++u) hx0 = __builtin_fmaf(hx0, 1.0000001f, 1.0e-9f);
            asm volatile("" : "+v"(hx0));
            if (++spn > 500000u) dead = true;   // fail, don't hang
        }
        // one LDS write + ONE barrier per step
        #pragma unroll
        for (int c = 0; c < 4; ++c)
            svh[p][tid + 256 * c] = __uint_as_float((unsigned)v[c]);
        __syncthreads();

        const float4 s2 = *(const float4*)&svh[p][kb];
        const float4 s3 = *(const float4*)&svh[p][kb + 256];
        const float4 s4 = *(const float4*)&svh[p][kb + 512];
        const float4 s5 = *(const float4*)&svh[p][kb + 768];

        if (live) {
            // ---- gates GEMV: 4 rows, weights + h in regs ----
            float acc[4];
            #pragma unroll
            for (int q = 0; q < 4; ++q) {
                acc[q] = w[q][0].x*x0.x + w[q][0].y*x0.y + w[q][0].z*x0.z + w[q][0].w*x0.w
                       + w[q][1].x*x1.x + w[q][1].y*x1.y + w[q][1].z*x1.z + w[q][1].w*x1.w
                       + w[q][2].x*s2.x + w[q][2].y*s2.y + w[q][2].z*s2.z + w[q][2].w*s2.w
                       + w[q][3].x*s3.x + w[q][3].y*s3.y + w[q][3].z*s3.z + w[q][3].w*s3.w
                       + w[q][4].x*s4.x + w[q][4].y*s4.y + w[q][4].z*s4.z + w[q][4].w*s4.w
                       + w[q][5].x*s5.x + w[q][5].y*s5.y + w[q][5].z*s5.z + w[q][5].w*s5.w;
            }
            // DPP reduce: 4 independent 6-step chains, totals land in lane 63
            acc[0] = wave_sum_l63(acc[0]);
            acc[1] = wave_sum_l63(acc[1]);
            acc[2] = wave_sum_l63(acc[2]);
            acc[3] = wave_sum_l63(acc[3]);
            // activations (redundant on all lanes; only lane 63's are real)
            const float iv = sigmoid_f(acc[0] + bias[0]);
            const float fv = sigmoid_f(acc[1] + bias[1]);
            const float gv = tanh_f   (acc[2] + bias[2]);
            const float ov = sigmoid_f(acc[3] + bias[3]);
            c_state = fv * c_state + iv * gv;
            const float h = ov * tanh_f(c_state);
            if (lane == 63) {  // publish FIRST: critical path. RMW -> visible at MALL.
                (void)__hip_atomic_exchange(&bufp[(size_t)(p ^ 1) * HID + j],
                    ((ull)(unsigned)(t + 2) << 32) | (ull)__float_as_uint(h),
                    __ATOMIC_RELAXED, __HIP_MEMORY_SCOPE_AGENT);
            }
        }

        // ---- fused dense: logits[t-1] rows {wg*2, wg*2+1} (wait window) ----
        if (t > 0 && wv < 2) {
            float d = wd[0].x*s2.x + wd[0].y*s2.y + wd[0].z*s2.z + wd[0].w*s2.w
                    + wd[1].x*s3.x + wd[1].y*s3.y + wd[1].z*s3.z + wd[1].w*s3.w
                    + wd[2].x*s4.x + wd[2].y*s4.y + wd[2].z*s4.z + wd[2].w*s4.w
                    + wd[3].x*s5.x + wd[3].y*s5.y + wd[3].z*s5.z + wd[3].w*s5.w;
            d = wave_sum_l63(d);
            if (lane == 63)
                logits[(size_t)(t - 1) * NC + drow] = d + dbias;
        }

        // ---- post-publish heater: 4 parallel chains x 128 FMAs (r13) ----
        if (live) {
            #pragma unroll
            for (int u = 0; u < 128; ++u) {
                hx0 = __builtin_fmaf(hx0, 1.0000001f, 1.0e-9f);
                hx1 = __builtin_fmaf(hx1, 1.0000001f, 1.0e-9f);
                hx2 = __builtin_fmaf(hx2, 1.0000001f, 1.0e-9f);
                hx3 = __builtin_fmaf(hx3, 1.0000001f, 1.0e-9f);
            }
            asm volatile("" : "+v"(hx0), "+v"(hx1), "+v"(hx2), "+v"(hx3));
        }
    }
}

// ---------------- Kernel 2: P[t] = softmax_C(logits[t]) ----------------
__global__ __launch_bounds__(256) void softmaxC_k(
    const float* __restrict__ logits, float* __restrict__ P)
{
    const int tid = threadIdx.x;
    const int lane = tid & 63, wvv = tid >> 6;
    #pragma unroll
    for (int rr = 0; rr < 2; ++rr) {
        const int row = blockIdx.x * 8 + wvv * 2 + rr;
        const float4 a = *(const float4*)&logits[(size_t)row * NC + lane * 8];
        const float4 b = *(const float4*)&logits[(size_t)row * NC + lane * 8 + 4];
        float m = fmaxf(fmaxf(fmaxf(a.x, a.y), fmaxf(a.z, a.w)),
                        fmaxf(fmaxf(b.x, b.y), fmaxf(b.z, b.w)));
        #pragma unroll
        for (int off = 32; off; off >>= 1) m = fmaxf(m, __shfl_xor(m, off));
        float4 ea, eb;
        ea.x = expf(a.x - m); ea.y = expf(a.y - m); ea.z = expf(a.z - m); ea.w = expf(a.w - m);
        eb.x = expf(b.x - m); eb.y = expf(b.y - m); eb.z = expf(b.z - m); eb.w = expf(b.w - m);
        float s = ea.x + ea.y + ea.z + ea.w + eb.x + eb.y + eb.z + eb.w;
        #pragma unroll
        for (int off = 32; off; off >>= 1) s += __shfl_xor(s, off);
        const float inv = 1.f / s;
        ea.x *= inv; ea.y *= inv; ea.z *= inv; ea.w *= inv;
        eb.x *= inv; eb.y *= inv; eb.z *= inv; eb.w *= inv;
        *(float4*)&P[(size_t)row * NC + lane * 8]     = ea;
        *(float4*)&P[(size_t)row * NC + lane * 8 + 4] = eb;
    }
}

// ---------------- Kernel 3a: colsum[c] = sum_t exp(P[t][c]) ----------------
__global__ __launch_bounds__(256) void colsum_k(const float* __restrict__ P, float* __restrict__ cs)
{
    const int tid = threadIdx.x;
    const int c  = blockIdx.x * 16 + (tid & 15);
    const int tr = tid >> 4;
    float s = 0.f;
    #pragma unroll 8
    for (int t = tr; t < T_STEPS; t += 16) s += expf(P[(size_t)t * NC + c]);
    __shared__ float red[256];
    red[tid] = s; __syncthreads();
    for (int off = 128; off >= 16; off >>= 1) {
        if (tid < off) red[tid] += red[tid + off];
        __syncthreads();
    }
    if (tid < 16) cs[blockIdx.x * 16 + tid] = red[tid];
}

// ---------------- Kernel 3b: out = exp(P) / colsum ----------------
__global__ __launch_bounds__(256) void norm_k(float* P, const float* __restrict__ cs)
{
    size_t i = (size_t)blockIdx.x * 256 + threadIdx.x;
    const size_t n = (size_t)T_STEPS * NC;
    const size_t stride = (size_t)gridDim.x * 256;
    for (; i < n; i += stride) P[i] = expf(P[i]) / cs[i & (NC - 1)];
}

extern "C" void kernel_launch(void* const* d_in, const int* in_sizes, int n_in,
                              void* d_out, int out_size, void* d_ws, size_t ws_size,
                              hipStream_t stream) {
    const float* X    = (const float*)d_in[0];
    const float* h0   = (const float*)d_in[1];
    const float* c0   = (const float*)d_in[2];
    const float* W_ih = (const float*)d_in[3];
    const float* W_hh = (const float*)d_in[4];
    const float* b_ih = (const float*)d_in[5];
    const float* b_hh = (const float*)d_in[6];
    const float* Wd   = (const float*)d_in[7];
    const float* bd   = (const float*)d_in[8];
    float* out = (float*)d_out;

    char* ws = (char*)d_ws;
    ull*   bufp   = (ull*)ws;                    // [2][HID] epoch|h (16 KB)
    float* cs     = (float*)(ws + 16384);        // [NC]
    float* logits = (float*)(ws + 32768);        // [T, NC] (33.5 MB)

    init_k<<<1, HID, 0, stream>>>(h0, bufp);
    lstm_rec<<<NWG, TPB, 0, stream>>>(X, c0, W_ih, W_hh, b_ih, b_hh, Wd, bd, logits, bufp);
    softmaxC_k<<<T_STEPS / 8, 256, 0, stream>>>(logits, out);
    colsum_k<<<NC / 16, 256, 0, stream>>>(out, cs);
    norm_k<<<2048, 256, 0, stream>>>(out, cs);
}